// Round 1
// baseline (332.694 us; speedup 1.0000x reference)
//
#include <hip/hip_runtime.h>
#include <stdint.h>

#define IMG 28
#define OD 26
#define K_REAL 784
#define N_REAL 300
#define KPAD 800
#define NPAD 320
#define NT 20      // N tiles of 16
#define NKS 25     // K steps of 32
#define KS2N 10    // GEMM2 K steps (320/32)
#define BM 64
#define THREADS 256

typedef float f32x4 __attribute__((ext_vector_type(4)));
typedef short s16x8 __attribute__((ext_vector_type(8)));

__device__ __forceinline__ unsigned short f2bf(float f) {
  union { float f; uint32_t u; } v; v.f = f;
  uint32_t u = v.u;
  return (unsigned short)((u + 0x7fffu + ((u >> 16) & 1u)) >> 16);  // RNE
}

// ---------------- pack Weff = C^T * w1  into MFMA-B fragment order ----------
// layout: [ks(25)][nt(20)][lane(64)][8] bf16, lane = g*16 + (col&15), elem = k&7
__global__ void pack_weff(const float* __restrict__ conv_w,
                          const float* __restrict__ w1,
                          unsigned short* __restrict__ weffp) {
  int t = blockIdx.x * blockDim.x + threadIdx.x;
  if (t >= KPAD * NPAD) return;
  int i = t / NPAD;        // k (input pixel) 0..799
  int j = t - i * NPAD;    // col 0..319
  float v = 0.f;
  if (i < K_REAL && j < N_REAL) {
    int r = i / IMG, c = i % IMG;
#pragma unroll
    for (int kh = 0; kh < 3; ++kh) {
      int orr = r - kh;
      if (orr < 0 || orr >= OD) continue;
#pragma unroll
      for (int kw = 0; kw < 3; ++kw) {
        int occ = c - kw;
        if (occ < 0 || occ >= OD) continue;
        v += conv_w[kh * 3 + kw] * w1[(orr * OD + occ) * N_REAL + j];
      }
    }
  }
  int ks = i >> 5, i5 = i & 31, g = i5 >> 3, jj = i5 & 7;
  int nt = j >> 4, c16 = j & 15;
  int lane = g * 16 + c16;
  weffp[(((size_t)ks * NT + nt) * 64 + lane) * 8 + jj] = f2bf(v);
}

// ---------------- pack w2 (300x10 -> 320x16) into fragment order ------------
__global__ void pack_w2(const float* __restrict__ w2,
                        unsigned short* __restrict__ w2p) {
  int t = blockIdx.x * blockDim.x + threadIdx.x;
  if (t >= 320 * 16) return;
  int k = t >> 4, j = t & 15;
  float v = (k < N_REAL && j < 10) ? w2[k * 10 + j] : 0.f;
  int ks = k >> 5, g = (k & 31) >> 3, jj = k & 7;
  w2p[((size_t)ks * 64 + g * 16 + j) * 8 + jj] = f2bf(v);
}

// ---------------- fused: relu(x @ Weff + b1) @ w2 + b2 ----------------------
__global__ void __launch_bounds__(THREADS)
fused_kernel(const float* __restrict__ x,
             const float* __restrict__ b1,
             const float* __restrict__ b2,
             const unsigned short* __restrict__ weffp,
             const unsigned short* __restrict__ w2p,
             float* __restrict__ out) {
  __shared__ uint4 ldsbuf[41984 / 16];           // 2x20480 B bufs, reused as a1
  unsigned char* lds = (unsigned char*)ldsbuf;

  const int tid = threadIdx.x;
  const int wid = tid >> 6;
  const int lane = tid & 63;
  const int g = lane >> 4;
  const int c16 = lane & 15;
  const long row0 = (long)blockIdx.x * BM + wid * 16;

  const float* xrow = x + (size_t)(row0 + c16) * K_REAL + g * 8;

  f32x4 acc[NT];
#pragma unroll
  for (int i = 0; i < NT; ++i) acc[i] = f32x4{0.f, 0.f, 0.f, 0.f};

  // stage one 20 KB B-tile (K-step ks) into LDS buffer sel; 5 chunks per wave
#define STAGE(ks_, sel_)                                                        \
  {                                                                             \
    _Pragma("unroll")                                                           \
    for (int i_ = 0; i_ < 5; ++i_) {                                            \
      int ci_ = wid * 5 + i_;                                                   \
      const unsigned char* gsrc_ = (const unsigned char*)weffp +                \
          (size_t)(ks_) * 20480 + ci_ * 1024 + lane * 16;                       \
      __builtin_amdgcn_global_load_lds(                                         \
          (const __attribute__((address_space(1))) uint32_t*)gsrc_,             \
          (__attribute__((address_space(3))) uint32_t*)&lds[(sel_) * 20480 + ci_ * 1024], \
          16, 0, 0);                                                            \
    }                                                                           \
  }

  STAGE(0, 0);
  __syncthreads();

#pragma unroll 1
  for (int ks = 0; ks < NKS - 1; ++ks) {
    STAGE(ks + 1, (ks + 1) & 1);
    // A fragment straight from global (16 rows x 128 B contiguous per wave)
    f32x4 a0 = *(const f32x4*)(xrow + ks * 32);
    f32x4 a1v = *(const f32x4*)(xrow + ks * 32 + 4);
    s16x8 af;
#pragma unroll
    for (int j = 0; j < 4; ++j) {
      af[j] = (short)f2bf(a0[j]);
      af[j + 4] = (short)f2bf(a1v[j]);
    }
    const unsigned char* bufc = &lds[(ks & 1) * 20480];
#pragma unroll
    for (int nt = 0; nt < NT; ++nt) {
      s16x8 bfr = *(const s16x8*)(bufc + nt * 1024 + lane * 16);
      acc[nt] = __builtin_amdgcn_mfma_f32_16x16x32_bf16(af, bfr, acc[nt], 0, 0, 0);
    }
    __syncthreads();
  }
  {  // tail K-step ks=24: k = 768 + g*8 valid only for g<2 (784 real K)
    s16x8 af = s16x8{0, 0, 0, 0, 0, 0, 0, 0};
    if (g < 2) {
      f32x4 a0 = *(const f32x4*)(xrow + 24 * 32);
      f32x4 a1v = *(const f32x4*)(xrow + 24 * 32 + 4);
#pragma unroll
      for (int j = 0; j < 4; ++j) {
        af[j] = (short)f2bf(a0[j]);
        af[j + 4] = (short)f2bf(a1v[j]);
      }
    }
    const unsigned char* bufc = &lds[0];  // 24&1 == 0
#pragma unroll
    for (int nt = 0; nt < NT; ++nt) {
      s16x8 bfr = *(const s16x8*)(bufc + nt * 1024 + lane * 16);
      acc[nt] = __builtin_amdgcn_mfma_f32_16x16x32_bf16(af, bfr, acc[nt], 0, 0, 0);
    }
  }
  __syncthreads();  // all B reads done; LDS reused for a1

  // epilogue: +b1, relu, a1 -> LDS bf16 (row stride 328 to avoid conflicts)
  unsigned short* a1w = (unsigned short*)(void*)&lds[wid * 10496];
  const int rbase = g * 4;
#pragma unroll
  for (int nt = 0; nt < NT; ++nt) {
    int col = nt * 16 + c16;
    float bias = (col < N_REAL) ? b1[col] : 0.f;
#pragma unroll
    for (int r = 0; r < 4; ++r) {
      float v = acc[nt][r] + bias;
      v = v > 0.f ? v : 0.f;
      a1w[(rbase + r) * 328 + col] = f2bf(v);
    }
  }
  __syncthreads();

  // GEMM2: 16x16 out tile per wave, K2 = 320
  f32x4 acc2 = f32x4{0.f, 0.f, 0.f, 0.f};
#pragma unroll
  for (int ks2 = 0; ks2 < KS2N; ++ks2) {
    s16x8 a2 = *(const s16x8*)((const unsigned char*)a1w + c16 * 656 + ks2 * 64 + g * 16);
    s16x8 b2f = *(const s16x8*)(w2p + ((size_t)ks2 * 64 + lane) * 8);
    acc2 = __builtin_amdgcn_mfma_f32_16x16x32_bf16(a2, b2f, acc2, 0, 0, 0);
  }
  if (c16 < 10) {
    float bv = b2[c16];
#pragma unroll
    for (int r = 0; r < 4; ++r) {
      long grow = row0 + rbase + r;
      out[grow * 10 + c16] = acc2[r] + bv;
    }
  }
}

extern "C" void kernel_launch(void* const* d_in, const int* in_sizes, int n_in,
                              void* d_out, int out_size, void* d_ws, size_t ws_size,
                              hipStream_t stream) {
  const float* x      = (const float*)d_in[0];
  const float* conv_w = (const float*)d_in[1];
  const float* w1     = (const float*)d_in[2];
  const float* b1     = (const float*)d_in[3];
  const float* w2     = (const float*)d_in[4];
  const float* b2     = (const float*)d_in[5];
  float* out = (float*)d_out;
  const int B = in_sizes[0] / K_REAL;

  unsigned short* weffp = (unsigned short*)d_ws;                     // 512000 B
  unsigned short* w2p   = (unsigned short*)((char*)d_ws + 512000);   // 10240 B

  pack_weff<<<(KPAD * NPAD + 255) / 256, 256, 0, stream>>>(conv_w, w1, weffp);
  pack_w2<<<(320 * 16 + 255) / 256, 256, 0, stream>>>(w2, w2p);
  fused_kernel<<<B / BM, THREADS, 0, stream>>>(x, b1, b2, weffp, w2p, out);
}